// Round 18
// baseline (298.560 us; speedup 1.0000x reference)
//
#include <hip/hip_runtime.h>

typedef __attribute__((ext_vector_type(8))) _Float16 f16x8;
typedef __attribute__((ext_vector_type(4))) _Float16 f16x4;
typedef __attribute__((ext_vector_type(4))) float f32x4;

// async global->LDS, 16B per lane; LDS dest = wave-uniform base + lane*16
__device__ inline void gl_lds16(const void* g, void* l) {
  __builtin_amdgcn_global_load_lds(
      (const __attribute__((address_space(1))) unsigned int*)g,
      (__attribute__((address_space(3))) unsigned int*)l, 16, 0, 0);
}

// ---------------- zero-init scratch (graph-replay safe) ----------------
__global__ __launch_bounds__(256) void zero_k(float* __restrict__ g, float* __restrict__ n) {
  int i = (blockIdx.x << 8) + threadIdx.x;
  if (i < 262144) g[i] = 0.f;
  if (i < 12288) n[i] = 0.f;
}

// ---------------- x (f32) -> x_hi (f16) ----------------
__global__ __launch_bounds__(256) void split_x_k(
    const float* __restrict__ x, _Float16* __restrict__ hi) {
  int i = (blockIdx.x << 8) + threadIdx.x;      // one float4 each
  float4 v = ((const float4*)x)[i];
  f16x4 h;
  h[0] = (_Float16)v.x; h[1] = (_Float16)v.y;
  h[2] = (_Float16)v.z; h[3] = (_Float16)v.w;
  *(f16x4*)&hi[(size_t)i << 2] = h;
}

// W_qkv (512x1536) -> Wt_hi (1536x512) f16; LDS-tiled 32x32 transpose
__global__ __launch_bounds__(256) void split_wt_k(
    const float* __restrict__ w, _Float16* __restrict__ hi) {
  __shared__ float tile[32][33];
  int k0 = blockIdx.x << 5;                     // 16 blocks over k
  int n0 = blockIdx.y << 5;                     // 48 blocks over n
  int r = threadIdx.x >> 5, c = threadIdx.x & 31;
#pragma unroll
  for (int i = 0; i < 4; ++i)
    tile[r + (i << 3)][c] = w[(size_t)(k0 + r + (i << 3)) * 1536 + n0 + c];
  __syncthreads();
#pragma unroll
  for (int i = 0; i < 4; ++i) {
    int n = r + (i << 3), k = c;
    hi[(size_t)(n0 + n) * 512 + k0 + k] = (_Float16)tile[k][n];
  }
}

// ---------------- f16 MFMA GEMM: qkv16 = x @ W_qkv (f16 out), K=512 ----------------
// 256x256 tile, BK=64 as two 32-k slots -> 16 phases (pair = (tile,slot)).
// 4 A-regions + 4 B-regions of 16KB rotate by pair&3 (128KB LDS, 1 blk/CU).
// Per phase: stage pair ph+3, counted vmcnt(12) (T4; drain 8/4/0 only in
// tail), barrier, 12x ds_read_b128 (r5-proven conflict-free swizzle, T2),
// setprio (T5), 32 MFMA, barrier.  K-order = 16 ascending K=32 steps ==
// r17's order -> bit-identical output.  Epilogue = r6-verified 256² C-write.
// Race audit: region (ph+3)&3 written at ph was last read at ph-1 (trailing
// barrier separates); reads gated by per-wave vmcnt + barrier.
__global__ __launch_bounds__(512, 1) void gemm_qkv_k(
    const _Float16* __restrict__ xhi, const _Float16* __restrict__ whi,
    _Float16* __restrict__ qkv) {
  __shared__ _Float16 As[4][256 * 32];   // [region][row][32k], 64B rows
  __shared__ _Float16 Bs[4][256 * 32];
  const int tid = threadIdx.x;
  const int lane = tid & 63;
  const int wave = tid >> 6;
  // T1: nwg=768 % 8 == 0 -> each XCD owns 96 consecutive wg = 16 bm panels.
  const int orig = blockIdx.x;
  const int wg = ((orig & 7) * 96) + (orig >> 3);
  const int bm = wg / 6;                 // 0..127
  const int bn = wg - bm * 6;            // 0..5
  const int wm = (wave >> 2) << 7;       // 0,128
  const int wn = (wave & 3) << 6;        // 0,64,128,192
  const int lhi = lane >> 4, llo = lane & 15;

  f32x4 zero = {};
  f32x4 acc[8][4];
#pragma unroll
  for (int i = 0; i < 8; ++i)
#pragma unroll
    for (int j = 0; j < 4; ++j) acc[i][j] = zero;

  // staging: 4 loads/thread per pair (A.h0, A.h1, B.h0, B.h1), linear LDS
  const int row0 = tid >> 2;                               // 0..127
  const int srcc = (((tid & 3) ^ ((tid >> 3) & 3)) << 3);  // chunk involution
  const size_t arow0 = (size_t)(bm * 256 + row0) * 512;
  const size_t arow1 = (size_t)(bm * 256 + 128 + row0) * 512;
  const size_t brow0 = (size_t)(bn * 256 + row0) * 512;
  const size_t brow1 = (size_t)(bn * 256 + 128 + row0) * 512;
  const int ld0 = tid << 3;              // elems (round 0: rows 0..127)
  const int ld1 = 4096 + (tid << 3);     // round 1: rows 128..255

  auto stage_pair = [&](int p) {         // p = 0..15
    const int reg = p & 3;
    const int kof = ((p >> 1) << 6) + ((p & 1) << 5) + srcc;
    gl_lds16(xhi + arow0 + kof, &As[reg][ld0]);
    gl_lds16(xhi + arow1 + kof, &As[reg][ld1]);
    gl_lds16(whi + brow0 + kof, &Bs[reg][ld0]);
    gl_lds16(whi + brow1 + kof, &Bs[reg][ld1]);
  };

  stage_pair(0); stage_pair(1); stage_pair(2);
  const int ksw = ((lhi ^ ((llo >> 1) & 3)) << 3);

  for (int ph = 0; ph < 16; ++ph) {
    if (ph <= 12) stage_pair(ph + 3);
    if (ph <= 12) {
      asm volatile("s_waitcnt vmcnt(12)" ::: "memory");  // pairs <= ph retired
    } else if (ph == 13) {
      asm volatile("s_waitcnt vmcnt(8)" ::: "memory");
    } else if (ph == 14) {
      asm volatile("s_waitcnt vmcnt(4)" ::: "memory");
    } else {
      asm volatile("s_waitcnt vmcnt(0)" ::: "memory");
    }
    __builtin_amdgcn_s_barrier();        // pair ph resident block-wide
    __builtin_amdgcn_sched_barrier(0);
    const int reg = ph & 3;
    f16x8 bf[4];
#pragma unroll
    for (int ni = 0; ni < 4; ++ni)
      bf[ni] = *(const f16x8*)&Bs[reg][(wn + (ni << 4) + llo) * 32 + ksw];
    __builtin_amdgcn_s_setprio(1);
#pragma unroll
    for (int mi = 0; mi < 8; ++mi) {
      f16x8 af = *(const f16x8*)&As[reg][(wm + (mi << 4) + llo) * 32 + ksw];
      acc[mi][0] = __builtin_amdgcn_mfma_f32_16x16x32_f16(af, bf[0], acc[mi][0], 0, 0, 0);
      acc[mi][1] = __builtin_amdgcn_mfma_f32_16x16x32_f16(af, bf[1], acc[mi][1], 0, 0, 0);
      acc[mi][2] = __builtin_amdgcn_mfma_f32_16x16x32_f16(af, bf[2], acc[mi][2], 0, 0, 0);
      acc[mi][3] = __builtin_amdgcn_mfma_f32_16x16x32_f16(af, bf[3], acc[mi][3], 0, 0, 0);
    }
    __builtin_amdgcn_s_setprio(0);
    __builtin_amdgcn_sched_barrier(0);
    __builtin_amdgcn_s_barrier();        // reads of region ph&3 done
  }
#pragma unroll
  for (int mi = 0; mi < 8; ++mi) {
    const int r0 = (bm << 8) + wm + (mi << 4) + (lhi << 2);
#pragma unroll
    for (int ni = 0; ni < 4; ++ni) {
      const int col = (bn << 8) + wn + (ni << 4) + llo;
      _Float16* p = qkv + (size_t)r0 * 1536 + col;
#pragma unroll
      for (int r = 0; r < 4; ++r) p[(size_t)r * 1536] = (_Float16)acc[mi][ni][r];
    }
  }
}

// ---------------- depthwise k=3 conv over T + per-channel sum of squares ----------------
// r17-proven: 384-thread pair-chunk blocks, LDS pair-reduce, NO atomics
__global__ __launch_bounds__(384) void dwconv_k(
    const _Float16* __restrict__ qkv, const float* __restrict__ w3,
    _Float16* __restrict__ qkvc, float* __restrict__ partials) {
  __shared__ float ssb[192][8];
  const int tid = threadIdx.x;
  const int sub = (tid >= 192) ? 1 : 0;
  const int g = tid - sub * 192;                // 0..191 channel-group
  const int c0 = g << 3;
  const int blk = blockIdx.x;                   // b*64 + pair
  const int b = blk >> 6;
  const int pair = blk & 63;
  const int t0 = (pair << 6) + (sub << 5);      // 32-t chunk
  const _Float16* base = qkv + ((size_t)((b << 12) + t0)) * 1536 + c0;
  _Float16* obase = qkvc + ((size_t)((b << 12) + t0)) * 1536 + c0;
  float w0[8], w1[8], w2[8];
#pragma unroll
  for (int j = 0; j < 8; ++j) {
    w0[j] = w3[(c0 + j) * 3 + 0];
    w1[j] = w3[(c0 + j) * 3 + 1];
    w2[j] = w3[(c0 + j) * 3 + 2];
  }
  f16x8 zero8 = {};
  f16x8 pv = (t0 == 0) ? zero8 : *(const f16x8*)&base[-1536];
  f16x8 cv = *(const f16x8*)&base[0];
  float ss[8] = {};
#pragma unroll 4
  for (int i = 0; i < 32; ++i) {
    f16x8 nv = (t0 + i == 4095) ? zero8 : *(const f16x8*)&base[(size_t)(i + 1) * 1536];
    f16x8 o;
#pragma unroll
    for (int j = 0; j < 8; ++j) {
      float of = (float)pv[j] * w0[j] + (float)cv[j] * w1[j] + (float)nv[j] * w2[j];
      _Float16 oh = (_Float16)of;
      o[j] = oh;
      float orf = (float)oh;
      ss[j] += orf * orf;
    }
    *(f16x8*)&obase[(size_t)i * 1536] = o;
    pv = cv; cv = nv;
  }
  if (sub) {
#pragma unroll
    for (int j = 0; j < 8; ++j) ssb[g][j] = ss[j];
  }
  __syncthreads();
  if (!sub) {
    float* pp = partials + ((size_t)pair) * 12288 + b * 1536 + c0;
    *(float4*)pp = make_float4(ss[0] + ssb[g][0], ss[1] + ssb[g][1],
                               ss[2] + ssb[g][2], ss[3] + ssb[g][3]);
    *(float4*)(pp + 4) = make_float4(ss[4] + ssb[g][4], ss[5] + ssb[g][5],
                                     ss[6] + ssb[g][6], ss[7] + ssb[g][7]);
  }
}

// norms[i] = sum over 64 t-chunks of partials[ch][i]
__global__ __launch_bounds__(256) void reduce_norms_k(
    const float* __restrict__ partials, float* __restrict__ norms) {
  int i = (blockIdx.x << 8) + threadIdx.x;      // < 12288
  float s = 0.f;
  for (int ch = 0; ch < 64; ++ch) s += partials[(size_t)ch * 12288 + i];
  norms[i] = s;
}

// ---------------- attention Gram via MFMA: G[c][d] = sum_t q_c k_d ----------------
// r16-proven: 256 t per block in two 128-t transposed LDS chunks; 4 waves x
// (16-c strip x 64 d); fragment/epilogue map identical to gemm.
__global__ __launch_bounds__(256) void attn_gram_k(
    const _Float16* __restrict__ qkvc, float* __restrict__ Gbuf) {
  int bh = blockIdx.x;  int b = bh >> 3, h = bh & 7;
  int tq = blockIdx.y;                           // 16 chunks of 256 t
  __shared__ _Float16 qT[64][136];   // [c][t] 128 t + pad
  __shared__ _Float16 kT[64][136];
  const int tid = threadIdx.x;
  const int wave = tid >> 6, lane = tid & 63;
  const int lhi = lane >> 4, llo = lane & 15;
  const int coff = h << 6;
  const int c0 = wave << 4;          // wave's 16-c output strip

  f32x4 zero = {};
  f32x4 acc[4];
#pragma unroll
  for (int i = 0; i < 4; ++i) acc[i] = zero;

  for (int ch = 0; ch < 2; ++ch) {
    __syncthreads();                 // prior chunk's fragment reads done
#pragma unroll
    for (int i = 0; i < 4; ++i) {
      int idx = (i << 8) + tid;
      int tl = idx >> 3, g = idx & 7;
      int t = (tq << 8) + (ch << 7) + tl;
      const _Float16* gp = qkvc + ((size_t)((b << 12) + t)) * 1536 + coff + (g << 3);
      f16x8 qv = *(const f16x8*)gp;
      f16x8 kv = *(const f16x8*)(gp + 512);
#pragma unroll
      for (int j = 0; j < 8; ++j) {
        qT[(g << 3) + j][tl] = qv[j];
        kT[(g << 3) + j][tl] = kv[j];
      }
    }
    __syncthreads();
#pragma unroll
    for (int kt = 0; kt < 4; ++kt) {
      const int toff = (kt << 5) + (lhi << 3);
      f16x8 af = *(const f16x8*)&qT[c0 + llo][toff];
#pragma unroll
      for (int di = 0; di < 4; ++di) {
        f16x8 bf = *(const f16x8*)&kT[(di << 4) + llo][toff];
        acc[di] = __builtin_amdgcn_mfma_f32_16x16x32_f16(af, bf, acc[di], 0, 0, 0);
      }
    }
  }
  float* Gp = Gbuf + ((size_t)bh << 12);
#pragma unroll
  for (int di = 0; di < 4; ++di)
#pragma unroll
    for (int r = 0; r < 4; ++r)
      atomicAdd(&Gp[(c0 + (lhi << 2) + r) * 64 + (di << 4) + llo], acc[di][r]);
}

// ---------------- softmax over d with L2-norm scaling + temperature ----------------
__global__ __launch_bounds__(256) void attn_softmax_k(
    const float* __restrict__ Gbuf, const float* __restrict__ norms,
    const float* __restrict__ temp, float* __restrict__ attn) {
  int tid = threadIdx.x;
  int sub = tid >> 6, c = tid & 63;              // 4 bh per block
  int bh = (blockIdx.x << 2) + sub;
  int b = bh >> 3, h = bh & 7;
  __shared__ float nk[4][64];
  float nq = fmaxf(sqrtf(norms[b * 1536 + (h << 6) + c]), 1e-12f);
  nk[sub][c] = fmaxf(sqrtf(norms[b * 1536 + 512 + (h << 6) + c]), 1e-12f);
  __syncthreads();
  float inq = temp[h] / nq;
  const float* Gp = Gbuf + ((size_t)bh << 12) + c * 64;
  float mx = -3.0e38f;
  for (int d = 0; d < 64; ++d) mx = fmaxf(mx, Gp[d] / nk[sub][d] * inq);
  float s = 0.f;
  for (int d = 0; d < 64; ++d) s += expf(Gp[d] / nk[sub][d] * inq - mx);
  float inv = 1.0f / s;
  float* op = attn + ((size_t)bh << 12) + c * 64;
  for (int d = 0; d < 64; ++d) op[d] = expf(Gp[d] / nk[sub][d] * inq - mx) * inv;
}

// ---------------- out_att: out[b,t,h*64+c] += sum_e attn[c][e] * v[e][t] ----------------
__global__ __launch_bounds__(256) void attn_out_k(
    const _Float16* __restrict__ qkvc, const float* __restrict__ attn,
    float* __restrict__ out) {
  int blk = blockIdx.x;                          // ((b*8+h)*32 + tt)
  int tt = blk & 31, h = (blk >> 5) & 7, b = blk >> 8;
  int t0 = tt << 7;                              // 128 t per block
  __shared__ float atT[64][68];                  // [e][c]
  __shared__ float vbT[64][132];                 // [e][t]
  int tid = threadIdx.x;
  const float* ap = attn + ((size_t)((b << 3) + h) << 12);
#pragma unroll
  for (int i = 0; i < 16; ++i) {
    int idx = (i << 8) + tid;  int c2 = idx >> 6, e = idx & 63;
    atT[e][c2] = ap[idx];
  }
#pragma unroll
  for (int i = 0; i < 4; ++i) {
    int idx = (i << 8) + tid;                    // 0..1023
    int t = idx >> 3, e8 = (idx & 7) << 3;
    f16x8 v = *(const f16x8*)&qkvc[((size_t)((b << 12) + t0 + t)) * 1536 + 1024 + (h << 6) + e8];
#pragma unroll
    for (int j = 0; j < 8; ++j) vbT[e8 + j][t] = (float)v[j];
  }
  __syncthreads();
  int tg = tid >> 4, cg = tid & 15;              // 8 t x 4 c per thread
  float acc[8][4] = {};
#pragma unroll 2
  for (int e = 0; e < 64; ++e) {
    float4 av = *(const float4*)&atT[e][cg << 2];
    float4 v0 = *(const float4*)&vbT[e][tg << 3];
    float4 v1 = *(const float4*)&vbT[e][(tg << 3) + 4];
    float va[8] = {v0.x, v0.y, v0.z, v0.w, v1.x, v1.y, v1.z, v1.w};
    float aa[4] = {av.x, av.y, av.z, av.w};
#pragma unroll
    for (int j = 0; j < 8; ++j)
#pragma unroll
      for (int i = 0; i < 4; ++i) acc[j][i] += va[j] * aa[i];
  }
#pragma unroll
  for (int j = 0; j < 8; ++j) {
    int t = t0 + (tg << 3) + j;
    float* op = &out[(((size_t)((b << 12) + t)) << 9) + (h << 6) + (cg << 2)];
    float4 prev = *(const float4*)op;
    float4 st = make_float4(acc[j][0] + prev.x, acc[j][1] + prev.y,
                            acc[j][2] + prev.z, acc[j][3] + prev.w);
    *(float4*)op = st;
  }
}

// ---------------- FUSED fc + grouped conv (9in->8out, k=3) + INLINE ctx chain ----
// r15-proven; STORES out (runs before attn_out, which accumulates).
__global__ __launch_bounds__(256) void conv2_k(
    const _Float16* __restrict__ qkvc, const float* __restrict__ x,
    const float* __restrict__ wfc, const float* __restrict__ bfc,
    const float* __restrict__ wdep, const float* __restrict__ bdep,
    const float* __restrict__ w1, const float* __restrict__ w2,
    float* __restrict__ out) {
  __shared__ _Float16 fs[18][576];    // f rows t0-1 .. t0+16 (u = n*64+c)
  __shared__ float wfcs[216];
  __shared__ float bfcs[9];
  int b = blockIdx.x >> 8;
  int t0 = (blockIdx.x & 255) << 4;   // 16 t per block
  int tid = threadIdx.x;
  if (tid < 216) wfcs[tid] = wfc[tid];
  else if (tid < 225) bfcs[tid - 216] = bfc[tid - 216];
  __syncthreads();                     // wfcs/bfcs visible

  // phase F: fc tile — 144 tasks (18 rows x 8 c-groups), fc_k's inner loop
  if (tid < 144) {
    int row = tid / 8, cg = tid & 7;
    int t = t0 - 1 + row;
    int cbase = cg << 3;
    if (t >= 0 && t < 4096) {
      const _Float16* q = qkvc + ((size_t)((b << 12) + t)) * 1536 + cbase;
      float acc9[9][8];
#pragma unroll
      for (int n = 0; n < 9; ++n) {
        float bv = bfcs[n];
#pragma unroll
        for (int j = 0; j < 8; ++j) acc9[n][j] = bv;
      }
      for (int m = 0; m < 24; ++m) {
        f16x8 v = *(const f16x8*)&q[m << 6];
        float vf[8];
#pragma unroll
        for (int j = 0; j < 8; ++j) vf[j] = (float)v[j];
#pragma unroll
        for (int n = 0; n < 9; ++n) {
          float w = wfcs[m * 9 + n];
#pragma unroll
          for (int j = 0; j < 8; ++j) acc9[n][j] += w * vf[j];
        }
      }
#pragma unroll
      for (int n = 0; n < 9; ++n) {
        f16x8 o;
#pragma unroll
        for (int j = 0; j < 8; ++j) o[j] = (_Float16)acc9[n][j];
        *(f16x8*)&fs[row][(n << 6) + cbase] = o;
      }
    } else {
      f16x8 z = {};
#pragma unroll
      for (int n = 0; n < 9; ++n) *(f16x8*)&fs[row][(n << 6) + cbase] = z;
    }
  }
  __syncthreads();

  // phase C: per output channel, rolling stencil; ctx1 computed inline
#pragma unroll
  for (int pass = 0; pass < 2; ++pass) {
    int o = (pass << 8) + tid;
    int g9 = (o >> 3) * 9;
    float wd[27];
#pragma unroll
    for (int q = 0; q < 27; ++q) wd[q] = wdep[o * 27 + q];
    float w2r[5];
#pragma unroll
    for (int p = 0; p < 5; ++p) w2r[p] = w2[o * 5 + p];
    float bd = bdep[o];
    float w10 = w1[o * 3], w11 = w1[o * 3 + 1], w12 = w1[o * 3 + 2];
    const float* xb = x + ((size_t)(b << 12)) * 512 + o;

    int tp0 = t0 - 2;
    float xm = (tp0 - 1 >= 0) ? xb[(size_t)(tp0 - 1) * 512] : 0.f;
    float xc = (tp0 >= 0 && tp0 < 4096) ? xb[(size_t)tp0 * 512] : 0.f;
    float cv4[4];
#pragma unroll
    for (int i = 0; i < 4; ++i) {
      int tp = tp0 + i;
      float xp = (tp + 1 >= 0 && tp + 1 < 4096) ? xb[(size_t)(tp + 1) * 512] : 0.f;
      float v = 0.f;
      if (tp >= 0 && tp < 4096)
        v = fmaxf(xm * w10 + xc * w11 + xp * w12, 0.f);
      cv4[i] = (float)(_Float16)v;
      xm = xc; xc = xp;
    }
    float c0 = cv4[0], cA = cv4[1], cB = cv4[2], cC = cv4[3];

    float f0[9], f1[9], f2[9];
#pragma unroll
    for (int i = 0; i < 9; ++i) {
      f0[i] = (float)fs[0][g9 + i];
      f1[i] = (float)fs[1][g9 + i];
    }
    float* ob = out + ((size_t)((b << 12) + t0)) * 512 + o;
    for (int tl = 0; tl < 16; ++tl) {
      int tp = t0 + 2 + tl;
      float xp = (tp + 1 < 4096) ? xb[(size_t)(tp + 1) * 512] : 0.f;
      float v4 = 0.f;
      if (tp < 4096) v4 = fmaxf(xm * w10 + xc * w11 + xp * w12, 0.f);
      float c4 = (float)(_Float16)v4;
      xm = xc; xc = xp;

      float s = bd;
#pragma unroll
      for (int i = 0; i < 9; ++i) f2[i] = (float)fs[tl + 2][g9 + i];
#pragma unroll
      for (int i = 0; i < 9; ++i)
        s += f0[i] * wd[i * 3 + 0] + f1[i] * wd[i * 3 + 1] + f2[i] * wd[i * 3 + 2];
      s += c0 * w2r[0] + cA * w2r[1] + cB * w2r[2] + cC * w2r[3] + c4 * w2r[4];
      ob[(size_t)tl * 512] = s;               // STORE (attn_out accumulates after)
#pragma unroll
      for (int i = 0; i < 9; ++i) { f0[i] = f1[i]; f1[i] = f2[i]; }
      c0 = cA; cA = cB; cB = cC; cC = c4;
    }
  }
}

extern "C" void kernel_launch(void* const* d_in, const int* in_sizes, int n_in,
                              void* d_out, int out_size, void* d_ws, size_t ws_size,
                              hipStream_t stream) {
  (void)in_sizes; (void)n_in; (void)out_size; (void)ws_size;
  const float* x        = (const float*)d_in[0];
  const float* W_qkv    = (const float*)d_in[1];
  const float* w_qkv_dw = (const float*)d_in[2];
  const float* w_ctx1   = (const float*)d_in[3];
  const float* w_ctx2   = (const float*)d_in[4];
  const float* W_fc     = (const float*)d_in[5];
  const float* b_fc     = (const float*)d_in[6];
  const float* w_dep    = (const float*)d_in[7];
  const float* b_dep    = (const float*)d_in[8];
  const float* temperature = (const float*)d_in[9];
  float* out = (float*)d_out;

  // workspace layout (r12-proven coarse envelope, ~206.6MB):
  //   [0,   96M)      qkvc (overlays xhi, dead after gemm)
  //   [96M, 99M)      whi (dead after gemm) / partials (64 rows x 12288 f32)
  //   [99M, 195M)     qkv16 (dead after dwconv)
  //   [195M..206.6M)  Gbuf (1M), attn (1M), norms (48K)
  char* ws = (char*)d_ws;
  _Float16* xhi  = (_Float16*)(ws);
  _Float16* whi  = (_Float16*)(ws + 100663296);
  float* partials = (float*)(ws + 100663296);    // overlays whi (dead after gemm)
  _Float16* qkv16  = (_Float16*)(ws + 103809024);
  _Float16* qkvc16 = (_Float16*)(ws);            // overlays xhi (dead)
  char* tail = ws + 204472320;
  float* Gbuf  = (float*)(tail);
  float* attn  = (float*)(tail + 1048576);
  float* norms = (float*)(tail + 2097152);

  zero_k<<<1024, 256, 0, stream>>>(Gbuf, norms);
  split_x_k<<<16384, 256, 0, stream>>>(x, xhi);
  split_wt_k<<<dim3(16, 48), 256, 0, stream>>>(W_qkv, whi);
  gemm_qkv_k<<<768, 512, 0, stream>>>(xhi, whi, qkv16);
  dwconv_k<<<512, 384, 0, stream>>>(qkv16, w_qkv_dw, qkvc16, partials);
  reduce_norms_k<<<48, 256, 0, stream>>>(partials, norms);
  conv2_k<<<2048, 256, 0, stream>>>(qkvc16, x, W_fc, b_fc, w_dep, b_dep,
                                    w_ctx1, w_ctx2, out);
  attn_gram_k<<<dim3(64, 16), 256, 0, stream>>>(qkvc16, Gbuf);
  attn_softmax_k<<<16, 256, 0, stream>>>(Gbuf, norms, temperature, attn);
  attn_out_k<<<2048, 256, 0, stream>>>(qkvc16, attn, out);
}

// Round 19
// 293.216 us; speedup vs baseline: 1.0182x; 1.0182x over previous
//
#include <hip/hip_runtime.h>

typedef __attribute__((ext_vector_type(8))) _Float16 f16x8;
typedef __attribute__((ext_vector_type(4))) _Float16 f16x4;
typedef __attribute__((ext_vector_type(4))) float f32x4;

// async global->LDS, 16B per lane; LDS dest = wave-uniform base + lane*16
__device__ inline void gl_lds16(const void* g, void* l) {
  __builtin_amdgcn_global_load_lds(
      (const __attribute__((address_space(1))) unsigned int*)g,
      (__attribute__((address_space(3))) unsigned int*)l, 16, 0, 0);
}

// ---------------- zero-init scratch (graph-replay safe) ----------------
__global__ __launch_bounds__(256) void zero_k(float* __restrict__ g, float* __restrict__ n) {
  int i = (blockIdx.x << 8) + threadIdx.x;
  if (i < 262144) g[i] = 0.f;
  if (i < 12288) n[i] = 0.f;
}

// ---------------- x (f32) -> x_hi (f16) ----------------
__global__ __launch_bounds__(256) void split_x_k(
    const float* __restrict__ x, _Float16* __restrict__ hi) {
  int i = (blockIdx.x << 8) + threadIdx.x;      // one float4 each
  float4 v = ((const float4*)x)[i];
  f16x4 h;
  h[0] = (_Float16)v.x; h[1] = (_Float16)v.y;
  h[2] = (_Float16)v.z; h[3] = (_Float16)v.w;
  *(f16x4*)&hi[(size_t)i << 2] = h;
}

// W_qkv (512x1536) -> Wt_hi (1536x512) f16; LDS-tiled 32x32 transpose
__global__ __launch_bounds__(256) void split_wt_k(
    const float* __restrict__ w, _Float16* __restrict__ hi) {
  __shared__ float tile[32][33];
  int k0 = blockIdx.x << 5;                     // 16 blocks over k
  int n0 = blockIdx.y << 5;                     // 48 blocks over n
  int r = threadIdx.x >> 5, c = threadIdx.x & 31;
#pragma unroll
  for (int i = 0; i < 4; ++i)
    tile[r + (i << 3)][c] = w[(size_t)(k0 + r + (i << 3)) * 1536 + n0 + c];
  __syncthreads();
#pragma unroll
  for (int i = 0; i < 4; ++i) {
    int n = r + (i << 3), k = c;
    hi[(size_t)(n0 + n) * 512 + k0 + k] = (_Float16)tile[k][n];
  }
}

// ---------------- f16 MFMA GEMM: qkv16 = x @ W_qkv (f16 out), K=512 ----------------
// r17-PROVEN (77us, best of 4 structures tried: 2ph-drain 198, depth-2 77,
// 256^2-mono 207, 256^2-16phase ~82): 128x128 tile, BK=32, depth-2 prefetch
// (3 LDS bufs, 48KB -> 3 blk/CU), counted vmcnt (T3/T4), conflict-free
// chunk-involution swizzle (T2), setprio (T5), bijective XCD chunking (T1).
__global__ __launch_bounds__(256) void gemm_qkv_k(
    const _Float16* __restrict__ xhi, const _Float16* __restrict__ whi,
    _Float16* __restrict__ qkv) {
  __shared__ _Float16 As[3][128 * 32];   // [buf][m][k], 64B rows, 4x16B chunks
  __shared__ _Float16 Bs[3][128 * 32];   // [buf][n][k]
  const int tid = threadIdx.x;
  const int wave = tid >> 6, lane = tid & 63;
  // T1: nwg=3072 divisible by 8 -> wg = (orig%8)*384 + orig/8.
  const int orig = blockIdx.x;
  const int wg = ((orig & 7) * 384) + (orig >> 3);
  const int bm = wg / 12;               // 0..255
  const int bn = wg - bm * 12;          // 0..11
  const int wm = (wave >> 1) << 6, wn = (wave & 1) << 6;
  const int lhi = lane >> 4, llo = lane & 15;

  f32x4 zero = {};
  f32x4 acc[4][4];
#pragma unroll
  for (int i = 0; i < 4; ++i)
#pragma unroll
    for (int j = 0; j < 4; ++j) acc[i][j] = zero;

  const int srowA = (bm << 7) + (wave << 5) + (lane >> 2);
  const int srowB = (bn << 7) + (wave << 5) + (lane >> 2);
  // T2 stage-side: lane fetches PERMUTED 16B chunk of its 64B k-row
  const int kc = (((lane & 3) ^ ((lane >> 3) & 3)) << 3);
  const size_t aoff0 = ((size_t)srowA << 9) + kc;
  const size_t aoff1 = ((size_t)(srowA + 16) << 9) + kc;
  const size_t boff0 = ((size_t)srowB << 9) + kc;
  const size_t boff1 = ((size_t)(srowB + 16) << 9) + kc;
  const int wb0 = (wave << 5) << 5;           // wave-uniform LDS dest offsets
  const int wb1 = ((wave << 5) + 16) << 5;

  auto stage = [&](int buf, int kk) {
    const int k0 = kk << 5;
    gl_lds16(xhi + aoff0 + k0, &As[buf][wb0]);
    gl_lds16(xhi + aoff1 + k0, &As[buf][wb1]);
    gl_lds16(whi + boff0 + k0, &Bs[buf][wb0]);
    gl_lds16(whi + boff1 + k0, &Bs[buf][wb1]);
  };

  stage(0, 0);
  stage(1, 1);
  int cur = 0;
  for (int kk = 0; kk < 16; ++kk) {
    if (kk < 14) {
      stage((cur + 2) % 3, kk + 2);           // depth-2 prefetch stays in flight
      asm volatile("s_waitcnt vmcnt(8)" ::: "memory");  // tile kk's 4 retired
    } else if (kk == 14) {
      asm volatile("s_waitcnt vmcnt(4)" ::: "memory");
    } else {
      asm volatile("s_waitcnt vmcnt(0)" ::: "memory");
    }
    __builtin_amdgcn_s_barrier();             // all waves' tile-kk loads retired
    __builtin_amdgcn_sched_barrier(0);
    // T2 read-side: chunk = lhi ^ ((llo>>1)&3) -> 2-way bank aliasing (free)
    const int ksw = ((lhi ^ ((llo >> 1) & 3)) << 3);
    f16x8 af[4], bf[4];
#pragma unroll
    for (int mi = 0; mi < 4; ++mi)
      af[mi] = *(const f16x8*)&As[cur][((wm + (mi << 4) + llo) << 5) + ksw];
#pragma unroll
    for (int ni = 0; ni < 4; ++ni)
      bf[ni] = *(const f16x8*)&Bs[cur][((wn + (ni << 4) + llo) << 5) + ksw];
    __builtin_amdgcn_s_setprio(1);
#pragma unroll
    for (int mi = 0; mi < 4; ++mi)
#pragma unroll
      for (int ni = 0; ni < 4; ++ni)
        acc[mi][ni] = __builtin_amdgcn_mfma_f32_16x16x32_f16(af[mi], bf[ni], acc[mi][ni], 0, 0, 0);
    __builtin_amdgcn_s_setprio(0);
    __builtin_amdgcn_sched_barrier(0);
    __builtin_amdgcn_s_barrier();             // reads of buf[cur] done before restage
    cur = (cur + 1) % 3;
  }
#pragma unroll
  for (int mi = 0; mi < 4; ++mi) {
    const int row0 = (bm << 7) + wm + (mi << 4) + (lhi << 2);
#pragma unroll
    for (int ni = 0; ni < 4; ++ni) {
      const int col = (bn << 7) + wn + (ni << 4) + llo;
      _Float16* p = qkv + (size_t)row0 * 1536 + col;
#pragma unroll
      for (int r = 0; r < 4; ++r) p[(size_t)r * 1536] = (_Float16)acc[mi][ni][r];
    }
  }
}

// ---------------- depthwise k=3 conv over T + per-channel sum of squares ----------------
// r17-proven: 384-thread pair-chunk blocks, LDS pair-reduce, NO atomics
__global__ __launch_bounds__(384) void dwconv_k(
    const _Float16* __restrict__ qkv, const float* __restrict__ w3,
    _Float16* __restrict__ qkvc, float* __restrict__ partials) {
  __shared__ float ssb[192][8];
  const int tid = threadIdx.x;
  const int sub = (tid >= 192) ? 1 : 0;
  const int g = tid - sub * 192;                // 0..191 channel-group
  const int c0 = g << 3;
  const int blk = blockIdx.x;                   // b*64 + pair
  const int b = blk >> 6;
  const int pair = blk & 63;
  const int t0 = (pair << 6) + (sub << 5);      // 32-t chunk
  const _Float16* base = qkv + ((size_t)((b << 12) + t0)) * 1536 + c0;
  _Float16* obase = qkvc + ((size_t)((b << 12) + t0)) * 1536 + c0;
  float w0[8], w1[8], w2[8];
#pragma unroll
  for (int j = 0; j < 8; ++j) {
    w0[j] = w3[(c0 + j) * 3 + 0];
    w1[j] = w3[(c0 + j) * 3 + 1];
    w2[j] = w3[(c0 + j) * 3 + 2];
  }
  f16x8 zero8 = {};
  f16x8 pv = (t0 == 0) ? zero8 : *(const f16x8*)&base[-1536];
  f16x8 cv = *(const f16x8*)&base[0];
  float ss[8] = {};
#pragma unroll 4
  for (int i = 0; i < 32; ++i) {
    f16x8 nv = (t0 + i == 4095) ? zero8 : *(const f16x8*)&base[(size_t)(i + 1) * 1536];
    f16x8 o;
#pragma unroll
    for (int j = 0; j < 8; ++j) {
      float of = (float)pv[j] * w0[j] + (float)cv[j] * w1[j] + (float)nv[j] * w2[j];
      _Float16 oh = (_Float16)of;
      o[j] = oh;
      float orf = (float)oh;
      ss[j] += orf * orf;
    }
    *(f16x8*)&obase[(size_t)i * 1536] = o;
    pv = cv; cv = nv;
  }
  if (sub) {
#pragma unroll
    for (int j = 0; j < 8; ++j) ssb[g][j] = ss[j];
  }
  __syncthreads();
  if (!sub) {
    float* pp = partials + ((size_t)pair) * 12288 + b * 1536 + c0;
    *(float4*)pp = make_float4(ss[0] + ssb[g][0], ss[1] + ssb[g][1],
                               ss[2] + ssb[g][2], ss[3] + ssb[g][3]);
    *(float4*)(pp + 4) = make_float4(ss[4] + ssb[g][4], ss[5] + ssb[g][5],
                                     ss[6] + ssb[g][6], ss[7] + ssb[g][7]);
  }
}

// norms[i] = sum over 64 t-chunks of partials[ch][i]
__global__ __launch_bounds__(256) void reduce_norms_k(
    const float* __restrict__ partials, float* __restrict__ norms) {
  int i = (blockIdx.x << 8) + threadIdx.x;      // < 12288
  float s = 0.f;
  for (int ch = 0; ch < 64; ++ch) s += partials[(size_t)ch * 12288 + i];
  norms[i] = s;
}

// ---------------- attention Gram via MFMA: G[c][d] = sum_t q_c k_d ----------------
// r16-proven: 256 t per block in two 128-t transposed LDS chunks; 4 waves x
// (16-c strip x 64 d); fragment/epilogue map identical to gemm.
__global__ __launch_bounds__(256) void attn_gram_k(
    const _Float16* __restrict__ qkvc, float* __restrict__ Gbuf) {
  int bh = blockIdx.x;  int b = bh >> 3, h = bh & 7;
  int tq = blockIdx.y;                           // 16 chunks of 256 t
  __shared__ _Float16 qT[64][136];   // [c][t] 128 t + pad
  __shared__ _Float16 kT[64][136];
  const int tid = threadIdx.x;
  const int wave = tid >> 6, lane = tid & 63;
  const int lhi = lane >> 4, llo = lane & 15;
  const int coff = h << 6;
  const int c0 = wave << 4;          // wave's 16-c output strip

  f32x4 zero = {};
  f32x4 acc[4];
#pragma unroll
  for (int i = 0; i < 4; ++i) acc[i] = zero;

  for (int ch = 0; ch < 2; ++ch) {
    __syncthreads();                 // prior chunk's fragment reads done
#pragma unroll
    for (int i = 0; i < 4; ++i) {
      int idx = (i << 8) + tid;
      int tl = idx >> 3, g = idx & 7;
      int t = (tq << 8) + (ch << 7) + tl;
      const _Float16* gp = qkvc + ((size_t)((b << 12) + t)) * 1536 + coff + (g << 3);
      f16x8 qv = *(const f16x8*)gp;
      f16x8 kv = *(const f16x8*)(gp + 512);
#pragma unroll
      for (int j = 0; j < 8; ++j) {
        qT[(g << 3) + j][tl] = qv[j];
        kT[(g << 3) + j][tl] = kv[j];
      }
    }
    __syncthreads();
#pragma unroll
    for (int kt = 0; kt < 4; ++kt) {
      const int toff = (kt << 5) + (lhi << 3);
      f16x8 af = *(const f16x8*)&qT[c0 + llo][toff];
#pragma unroll
      for (int di = 0; di < 4; ++di) {
        f16x8 bf = *(const f16x8*)&kT[(di << 4) + llo][toff];
        acc[di] = __builtin_amdgcn_mfma_f32_16x16x32_f16(af, bf, acc[di], 0, 0, 0);
      }
    }
  }
  float* Gp = Gbuf + ((size_t)bh << 12);
#pragma unroll
  for (int di = 0; di < 4; ++di)
#pragma unroll
    for (int r = 0; r < 4; ++r)
      atomicAdd(&Gp[(c0 + (lhi << 2) + r) * 64 + (di << 4) + llo], acc[di][r]);
}

// ---------------- softmax over d with L2-norm scaling + temperature ----------------
__global__ __launch_bounds__(256) void attn_softmax_k(
    const float* __restrict__ Gbuf, const float* __restrict__ norms,
    const float* __restrict__ temp, float* __restrict__ attn) {
  int tid = threadIdx.x;
  int sub = tid >> 6, c = tid & 63;              // 4 bh per block
  int bh = (blockIdx.x << 2) + sub;
  int b = bh >> 3, h = bh & 7;
  __shared__ float nk[4][64];
  float nq = fmaxf(sqrtf(norms[b * 1536 + (h << 6) + c]), 1e-12f);
  nk[sub][c] = fmaxf(sqrtf(norms[b * 1536 + 512 + (h << 6) + c]), 1e-12f);
  __syncthreads();
  float inq = temp[h] / nq;
  const float* Gp = Gbuf + ((size_t)bh << 12) + c * 64;
  float mx = -3.0e38f;
  for (int d = 0; d < 64; ++d) mx = fmaxf(mx, Gp[d] / nk[sub][d] * inq);
  float s = 0.f;
  for (int d = 0; d < 64; ++d) s += expf(Gp[d] / nk[sub][d] * inq - mx);
  float inv = 1.0f / s;
  float* op = attn + ((size_t)bh << 12) + c * 64;
  for (int d = 0; d < 64; ++d) op[d] = expf(Gp[d] / nk[sub][d] * inq - mx) * inv;
}

// ---------------- out_att: out[b,t,h*64+c] += sum_e attn[c][e] * v[e][t] ----------------
__global__ __launch_bounds__(256) void attn_out_k(
    const _Float16* __restrict__ qkvc, const float* __restrict__ attn,
    float* __restrict__ out) {
  int blk = blockIdx.x;                          // ((b*8+h)*32 + tt)
  int tt = blk & 31, h = (blk >> 5) & 7, b = blk >> 8;
  int t0 = tt << 7;                              // 128 t per block
  __shared__ float atT[64][68];                  // [e][c]
  __shared__ float vbT[64][132];                 // [e][t]
  int tid = threadIdx.x;
  const float* ap = attn + ((size_t)((b << 3) + h) << 12);
#pragma unroll
  for (int i = 0; i < 16; ++i) {
    int idx = (i << 8) + tid;  int c2 = idx >> 6, e = idx & 63;
    atT[e][c2] = ap[idx];
  }
#pragma unroll
  for (int i = 0; i < 4; ++i) {
    int idx = (i << 8) + tid;                    // 0..1023
    int t = idx >> 3, e8 = (idx & 7) << 3;
    f16x8 v = *(const f16x8*)&qkvc[((size_t)((b << 12) + t0 + t)) * 1536 + 1024 + (h << 6) + e8];
#pragma unroll
    for (int j = 0; j < 8; ++j) vbT[e8 + j][t] = (float)v[j];
  }
  __syncthreads();
  int tg = tid >> 4, cg = tid & 15;              // 8 t x 4 c per thread
  float acc[8][4] = {};
#pragma unroll 2
  for (int e = 0; e < 64; ++e) {
    float4 av = *(const float4*)&atT[e][cg << 2];
    float4 v0 = *(const float4*)&vbT[e][tg << 3];
    float4 v1 = *(const float4*)&vbT[e][(tg << 3) + 4];
    float va[8] = {v0.x, v0.y, v0.z, v0.w, v1.x, v1.y, v1.z, v1.w};
    float aa[4] = {av.x, av.y, av.z, av.w};
#pragma unroll
    for (int j = 0; j < 8; ++j)
#pragma unroll
      for (int i = 0; i < 4; ++i) acc[j][i] += va[j] * aa[i];
  }
#pragma unroll
  for (int j = 0; j < 8; ++j) {
    int t = t0 + (tg << 3) + j;
    float* op = &out[(((size_t)((b << 12) + t)) << 9) + (h << 6) + (cg << 2)];
    float4 prev = *(const float4*)op;
    float4 st = make_float4(acc[j][0] + prev.x, acc[j][1] + prev.y,
                            acc[j][2] + prev.z, acc[j][3] + prev.w);
    *(float4*)op = st;
  }
}

// ---------------- FUSED fc + grouped conv (9in->8out, k=3) + INLINE ctx chain ----
// r15-proven; STORES out (runs before attn_out, which accumulates).
__global__ __launch_bounds__(256) void conv2_k(
    const _Float16* __restrict__ qkvc, const float* __restrict__ x,
    const float* __restrict__ wfc, const float* __restrict__ bfc,
    const float* __restrict__ wdep, const float* __restrict__ bdep,
    const float* __restrict__ w1, const float* __restrict__ w2,
    float* __restrict__ out) {
  __shared__ _Float16 fs[18][576];    // f rows t0-1 .. t0+16 (u = n*64+c)
  __shared__ float wfcs[216];
  __shared__ float bfcs[9];
  int b = blockIdx.x >> 8;
  int t0 = (blockIdx.x & 255) << 4;   // 16 t per block
  int tid = threadIdx.x;
  if (tid < 216) wfcs[tid] = wfc[tid];
  else if (tid < 225) bfcs[tid - 216] = bfc[tid - 216];
  __syncthreads();                     // wfcs/bfcs visible

  // phase F: fc tile — 144 tasks (18 rows x 8 c-groups), fc_k's inner loop
  if (tid < 144) {
    int row = tid / 8, cg = tid & 7;
    int t = t0 - 1 + row;
    int cbase = cg << 3;
    if (t >= 0 && t < 4096) {
      const _Float16* q = qkvc + ((size_t)((b << 12) + t)) * 1536 + cbase;
      float acc9[9][8];
#pragma unroll
      for (int n = 0; n < 9; ++n) {
        float bv = bfcs[n];
#pragma unroll
        for (int j = 0; j < 8; ++j) acc9[n][j] = bv;
      }
      for (int m = 0; m < 24; ++m) {
        f16x8 v = *(const f16x8*)&q[m << 6];
        float vf[8];
#pragma unroll
        for (int j = 0; j < 8; ++j) vf[j] = (float)v[j];
#pragma unroll
        for (int n = 0; n < 9; ++n) {
          float w = wfcs[m * 9 + n];
#pragma unroll
          for (int j = 0; j < 8; ++j) acc9[n][j] += w * vf[j];
        }
      }
#pragma unroll
      for (int n = 0; n < 9; ++n) {
        f16x8 o;
#pragma unroll
        for (int j = 0; j < 8; ++j) o[j] = (_Float16)acc9[n][j];
        *(f16x8*)&fs[row][(n << 6) + cbase] = o;
      }
    } else {
      f16x8 z = {};
#pragma unroll
      for (int n = 0; n < 9; ++n) *(f16x8*)&fs[row][(n << 6) + cbase] = z;
    }
  }
  __syncthreads();

  // phase C: per output channel, rolling stencil; ctx1 computed inline
#pragma unroll
  for (int pass = 0; pass < 2; ++pass) {
    int o = (pass << 8) + tid;
    int g9 = (o >> 3) * 9;
    float wd[27];
#pragma unroll
    for (int q = 0; q < 27; ++q) wd[q] = wdep[o * 27 + q];
    float w2r[5];
#pragma unroll
    for (int p = 0; p < 5; ++p) w2r[p] = w2[o * 5 + p];
    float bd = bdep[o];
    float w10 = w1[o * 3], w11 = w1[o * 3 + 1], w12 = w1[o * 3 + 2];
    const float* xb = x + ((size_t)(b << 12)) * 512 + o;

    int tp0 = t0 - 2;
    float xm = (tp0 - 1 >= 0) ? xb[(size_t)(tp0 - 1) * 512] : 0.f;
    float xc = (tp0 >= 0 && tp0 < 4096) ? xb[(size_t)tp0 * 512] : 0.f;
    float cv4[4];
#pragma unroll
    for (int i = 0; i < 4; ++i) {
      int tp = tp0 + i;
      float xp = (tp + 1 >= 0 && tp + 1 < 4096) ? xb[(size_t)(tp + 1) * 512] : 0.f;
      float v = 0.f;
      if (tp >= 0 && tp < 4096)
        v = fmaxf(xm * w10 + xc * w11 + xp * w12, 0.f);
      cv4[i] = (float)(_Float16)v;
      xm = xc; xc = xp;
    }
    float c0 = cv4[0], cA = cv4[1], cB = cv4[2], cC = cv4[3];

    float f0[9], f1[9], f2[9];
#pragma unroll
    for (int i = 0; i < 9; ++i) {
      f0[i] = (float)fs[0][g9 + i];
      f1[i] = (float)fs[1][g9 + i];
    }
    float* ob = out + ((size_t)((b << 12) + t0)) * 512 + o;
    for (int tl = 0; tl < 16; ++tl) {
      int tp = t0 + 2 + tl;
      float xp = (tp + 1 < 4096) ? xb[(size_t)(tp + 1) * 512] : 0.f;
      float v4 = 0.f;
      if (tp < 4096) v4 = fmaxf(xm * w10 + xc * w11 + xp * w12, 0.f);
      float c4 = (float)(_Float16)v4;
      xm = xc; xc = xp;

      float s = bd;
#pragma unroll
      for (int i = 0; i < 9; ++i) f2[i] = (float)fs[tl + 2][g9 + i];
#pragma unroll
      for (int i = 0; i < 9; ++i)
        s += f0[i] * wd[i * 3 + 0] + f1[i] * wd[i * 3 + 1] + f2[i] * wd[i * 3 + 2];
      s += c0 * w2r[0] + cA * w2r[1] + cB * w2r[2] + cC * w2r[3] + c4 * w2r[4];
      ob[(size_t)tl * 512] = s;               // STORE (attn_out accumulates after)
#pragma unroll
      for (int i = 0; i < 9; ++i) { f0[i] = f1[i]; f1[i] = f2[i]; }
      c0 = cA; cA = cB; cB = cC; cC = c4;
    }
  }
}

extern "C" void kernel_launch(void* const* d_in, const int* in_sizes, int n_in,
                              void* d_out, int out_size, void* d_ws, size_t ws_size,
                              hipStream_t stream) {
  (void)in_sizes; (void)n_in; (void)out_size; (void)ws_size;
  const float* x        = (const float*)d_in[0];
  const float* W_qkv    = (const float*)d_in[1];
  const float* w_qkv_dw = (const float*)d_in[2];
  const float* w_ctx1   = (const float*)d_in[3];
  const float* w_ctx2   = (const float*)d_in[4];
  const float* W_fc     = (const float*)d_in[5];
  const float* b_fc     = (const float*)d_in[6];
  const float* w_dep    = (const float*)d_in[7];
  const float* b_dep    = (const float*)d_in[8];
  const float* temperature = (const float*)d_in[9];
  float* out = (float*)d_out;

  // workspace layout (r12-proven coarse envelope, ~206.6MB):
  //   [0,   96M)      qkvc (overlays xhi, dead after gemm)
  //   [96M, 99M)      whi (dead after gemm) / partials (64 rows x 12288 f32)
  //   [99M, 195M)     qkv16 (dead after dwconv)
  //   [195M..206.6M)  Gbuf (1M), attn (1M), norms (48K)
  char* ws = (char*)d_ws;
  _Float16* xhi  = (_Float16*)(ws);
  _Float16* whi  = (_Float16*)(ws + 100663296);
  float* partials = (float*)(ws + 100663296);    // overlays whi (dead after gemm)
  _Float16* qkv16  = (_Float16*)(ws + 103809024);
  _Float16* qkvc16 = (_Float16*)(ws);            // overlays xhi (dead)
  char* tail = ws + 204472320;
  float* Gbuf  = (float*)(tail);
  float* attn  = (float*)(tail + 1048576);
  float* norms = (float*)(tail + 2097152);

  zero_k<<<1024, 256, 0, stream>>>(Gbuf, norms);
  split_x_k<<<16384, 256, 0, stream>>>(x, xhi);
  split_wt_k<<<dim3(16, 48), 256, 0, stream>>>(W_qkv, whi);
  gemm_qkv_k<<<3072, 256, 0, stream>>>(xhi, whi, qkv16);
  dwconv_k<<<512, 384, 0, stream>>>(qkv16, w_qkv_dw, qkvc16, partials);
  reduce_norms_k<<<48, 256, 0, stream>>>(partials, norms);
  conv2_k<<<2048, 256, 0, stream>>>(qkvc16, x, W_fc, b_fc, w_dep, b_dep,
                                    w_ctx1, w_ctx2, out);
  attn_gram_k<<<dim3(64, 16), 256, 0, stream>>>(qkvc16, Gbuf);
  attn_softmax_k<<<16, 256, 0, stream>>>(Gbuf, norms, temperature, attn);
  attn_out_k<<<2048, 256, 0, stream>>>(qkvc16, attn, out);
}